// Round 1
// baseline (709.487 us; speedup 1.0000x reference)
//
#include <hip/hip_runtime.h>

#define EPSF 1e-8f

typedef __attribute__((ext_vector_type(8))) short bf16x8;
typedef __attribute__((ext_vector_type(4))) float f32x4;

constexpr int Nv     = 10000;  // N (rows of F/H, dim of Dv)
constexpr int Ne     = 5000;   // E (cols of H, dim of De)
constexpr int Dd     = 128;    // d
constexpr int NPAD   = 10016;  // 313*32, K padded to multiple of 32
constexpr int EPAD   = 5120;   // 40*128, E padded to multiple of 128
constexpr int KSTEPS = 313;    // NPAD/32
constexpr int KSPLIT = 16;     // split-K factor -> 40*16 = 640 blocks
constexpr int STEPS_PER = (KSTEPS + KSPLIT - 1) / KSPLIT; // 20

__device__ __forceinline__ unsigned short f2bf_rne(float f) {
    unsigned int u = __builtin_bit_cast(unsigned int, f);
    u += 0x7fffu + ((u >> 16) & 1u);   // round-to-nearest-even
    return (unsigned short)(u >> 16);
}

// de_inv[e] = 1/(De[e,e]+eps) for e<E, 0 in the pad region (kills pad in reduce)
__global__ void prep_de_kernel(const float* __restrict__ De, float* __restrict__ de_inv) {
    int e = blockIdx.x * 256 + threadIdx.x;
    if (e < EPAD) de_inv[e] = (e < Ne) ? 1.0f / (De[(size_t)e * (Ne + 1)] + EPSF) : 0.0f;
}

// Fst[c][n] = bf16( F[n,c] * (Dv[n,n]+eps)^-1/2 ), n-contiguous rows (B-operand layout)
__global__ void prep_fst_kernel(const float* __restrict__ F, const float* __restrict__ Dv,
                                short* __restrict__ Fst) {
    int n = blockIdx.x * 256 + threadIdx.x;
    int c = blockIdx.y;
    if (n < NPAD) {
        unsigned short b = 0;
        if (n < Nv) {
            float s = 1.0f / sqrtf(Dv[(size_t)n * (Nv + 1)] + EPSF);
            b = f2bf_rne(F[(size_t)n * Dd + c] * s);
        }
        Fst[(size_t)c * NPAD + n] = (short)b;
    }
}

// sum(F*F) -> ws0[0]
__global__ void sum_ff_kernel(const float* __restrict__ F, float* __restrict__ out0) {
    const float4* F4 = (const float4*)F;
    int base = blockIdx.x * 512 + threadIdx.x;      // 625*512 = 320000 = N*d/4 exactly
    float4 a = F4[base];
    float4 b = F4[base + 256];
    float sum = a.x*a.x + a.y*a.y + a.z*a.z + a.w*a.w
              + b.x*b.x + b.y*b.y + b.z*b.z + b.w*b.w;
    #pragma unroll
    for (int off = 32; off; off >>= 1) sum += __shfl_down(sum, off);
    if ((threadIdx.x & 63) == 0) atomicAdd(out0, sum);
}

// Split-K GEMM: M[e,c] += sum_{n in split} H[n,e]*Fs[n,c]
// block tile 128e x 128c, K-chunk 32; A via LDS (fp32->bf16 transpose), B direct global.
__global__ __launch_bounds__(256, 2)
void gemm_split_kernel(const float* __restrict__ H, const short* __restrict__ Fst,
                       float* __restrict__ M) {
    // A_lds[e][kk]: 128 rows, 32 bf16 data + 8 bf16 pad = 80 B row stride (16B-aligned
    // b128 fragment reads; staging b32 writes land 2-way-per-bank = conflict-free)
    __shared__ unsigned int Alds[128 * 20];

    const int t  = threadIdx.x;
    const int w  = t >> 6;        // wave 0..3
    const int l  = t & 63;
    const int lm = l & 15;
    const int q  = l >> 4;        // quad 0..3
    const int e0 = blockIdx.x * 128;
    const int sb = blockIdx.y * STEPS_PER;
    const int se = min(sb + STEPS_PER, KSTEPS);

    const int rp  = t & 15;       // row-pair index: rows kk = 2rp, 2rp+1
    const int cp4 = t >> 4;       // col-pair base 0..15

    f32x4 acc[2][8];
    #pragma unroll
    for (int a = 0; a < 2; ++a)
        #pragma unroll
        for (int b = 0; b < 8; ++b) acc[a][b] = (f32x4){0.f, 0.f, 0.f, 0.f};

    for (int s = sb; s < se; ++s) {
        const int n0 = s * 32;

        // B fragments: 16 B contiguous per lane from pre-transposed bf16 Fst (L2-hot)
        bf16x8 Bf[8];
        #pragma unroll
        for (int cb = 0; cb < 8; ++cb) {
            const int c = cb * 16 + lm;
            Bf[cb] = *(const bf16x8*)(Fst + (size_t)c * NPAD + n0 + q * 8);
        }

        // A staging: 2x2 register micro-transpose H[n][e] -> Alds[e][kk] bf16
        const int n  = n0 + 2 * rp;
        const bool vn = (n < Nv);  // N even, pair shares validity
        #pragma unroll
        for (int j = 0; j < 4; ++j) {
            const int cp = cp4 + 16 * j;
            const int el = 2 * cp;
            const int e  = e0 + el;
            float2 a0 = make_float2(0.f, 0.f), a1 = make_float2(0.f, 0.f);
            if (vn && e < Ne) {    // E even, pair shares validity
                a0 = *(const float2*)(H + (size_t)n * Ne + e);
                a1 = *(const float2*)(H + (size_t)(n + 1) * Ne + e);
            }
            unsigned int w0 = (unsigned int)f2bf_rne(a0.x) | ((unsigned int)f2bf_rne(a1.x) << 16);
            unsigned int w1 = (unsigned int)f2bf_rne(a0.y) | ((unsigned int)f2bf_rne(a1.y) << 16);
            Alds[el * 20 + rp]       = w0;   // row e,   kk = 2rp,2rp+1
            Alds[(el + 1) * 20 + rp] = w1;   // row e+1
        }
        __syncthreads();

        // A fragments: A[m = lane&15][k = quad*8 + j], 16 B contiguous in LDS row
        bf16x8 Af[2];
        #pragma unroll
        for (int eb = 0; eb < 2; ++eb) {
            const int el = (2 * w + eb) * 16 + lm;
            Af[eb] = *(const bf16x8*)((const char*)Alds + el * 80 + q * 16);
        }
        __syncthreads();   // frags in regs; next iter may overwrite LDS

        #pragma unroll
        for (int cb = 0; cb < 8; ++cb)
            #pragma unroll
            for (int eb = 0; eb < 2; ++eb)
                acc[eb][cb] = __builtin_amdgcn_mfma_f32_16x16x32_bf16(
                    Af[eb], Bf[cb], acc[eb][cb], 0, 0, 0);
    }

    // epilogue: C/D layout col = lane&15, row = quad*4 + reg (HW-verified mapping)
    #pragma unroll
    for (int eb = 0; eb < 2; ++eb) {
        #pragma unroll
        for (int cb = 0; cb < 8; ++cb) {
            const int c = cb * 16 + lm;
            #pragma unroll
            for (int r = 0; r < 4; ++r) {
                const int el = (2 * w + eb) * 16 + q * 4 + r;
                atomicAdd(&M[(size_t)(e0 + el) * 128 + c], acc[eb][cb][r]);
            }
        }
    }
}

// S = sum_e de_inv[e] * ||M[e,:]||^2 -> ws0[1]
__global__ void reduce_m_kernel(const float* __restrict__ M, const float* __restrict__ de_inv,
                                float* __restrict__ outS) {
    const float4* M4 = (const float4*)M;
    int base = blockIdx.x * 512 + threadIdx.x;  // 320*512 = 163840 = EPAD*128/4 exactly
    float sum = 0.f;
    #pragma unroll
    for (int i = 0; i < 2; ++i) {
        int idx = base + i * 256;
        float4 m = M4[idx];
        float wgt = de_inv[idx >> 5];           // e = (idx*4)/128
        sum += wgt * (m.x*m.x + m.y*m.y + m.z*m.z + m.w*m.w);
    }
    #pragma unroll
    for (int off = 32; off; off >>= 1) sum += __shfl_down(sum, off);
    if ((threadIdx.x & 63) == 0) atomicAdd(outS, sum);
}

__global__ void final_kernel(const float* __restrict__ ws0, float* __restrict__ out) {
    out[0] = (ws0[0] - ws0[1]) * (1.0f / (float)Nv);
}

extern "C" void kernel_launch(void* const* d_in, const int* in_sizes, int n_in,
                              void* d_out, int out_size, void* d_ws, size_t ws_size,
                              hipStream_t stream) {
    (void)in_sizes; (void)n_in; (void)out_size; (void)ws_size;
    const float* F  = (const float*)d_in[0];
    const float* H  = (const float*)d_in[1];
    const float* Dv = (const float*)d_in[2];
    const float* De = (const float*)d_in[3];
    float* out = (float*)d_out;

    // workspace layout (floats): [0]=sumFF [1]=S | pad to 64B | M[EPAD*128] | de_inv[EPAD] | Fst(bf16)
    float* ws0    = (float*)d_ws;
    float* M      = ws0 + 16;
    float* de_inv = M + (size_t)EPAD * 128;
    short* Fst    = (short*)(de_inv + EPAD);   // 16B-aligned: offset 2641984

    // zero accumulators + M (ws is poisoned 0xAA before every call)
    hipMemsetAsync(d_ws, 0, 64 + (size_t)EPAD * 128 * 4, stream);

    prep_de_kernel <<<EPAD / 256, 256, 0, stream>>>(De, de_inv);
    prep_fst_kernel<<<dim3((NPAD + 255) / 256, 128), 256, 0, stream>>>(F, Dv, Fst);
    sum_ff_kernel  <<<625, 256, 0, stream>>>(F, ws0);
    gemm_split_kernel<<<dim3(EPAD / 128, KSPLIT), 256, 0, stream>>>(H, Fst, M);
    reduce_m_kernel<<<320, 256, 0, stream>>>(M, de_inv, ws0 + 1);
    final_kernel   <<<1, 1, 0, stream>>>(ws0, out);
}

// Round 2
// 700.351 us; speedup vs baseline: 1.0130x; 1.0130x over previous
//
#include <hip/hip_runtime.h>

#define EPSF 1e-8f

typedef __attribute__((ext_vector_type(8))) short bf16x8;
typedef __attribute__((ext_vector_type(4))) float f32x4;

constexpr int Nv     = 10000;  // N
constexpr int Ne     = 5000;   // E
constexpr int Dd     = 128;    // d
constexpr int NPAD   = 10016;  // 313*32
constexpr int EPAD   = 5120;   // 40*128
constexpr int KSTEPS = 313;    // NPAD/32
constexpr int KSPLIT = 12;     // 40*12 = 480 blocks = one residency round at 2 blocks/CU

__device__ __forceinline__ unsigned short f2bf_rne(float f) {
    unsigned int u = __builtin_bit_cast(unsigned int, f);
    u += 0x7fffu + ((u >> 16) & 1u);
    return (unsigned short)(u >> 16);
}

// dvis[n] = (Dv[n,n]+eps)^-1/2 (0 in pad) — hoists 1.28M strided diag reads to 10016
__global__ void prep_dv_kernel(const float* __restrict__ Dv, float* __restrict__ dvis) {
    int n = blockIdx.x * 256 + threadIdx.x;
    if (n < NPAD) dvis[n] = (n < Nv) ? rsqrtf(Dv[(size_t)n * (Nv + 1)] + EPSF) : 0.0f;
}

// Fst[c][n] = bf16(F[n,c] * dvis[n]); n-contiguous rows (B-operand layout). Writes coalesced.
__global__ void prep_fst_kernel(const float* __restrict__ F, const float* __restrict__ dvis,
                                short* __restrict__ Fst) {
    int n = blockIdx.x * 256 + threadIdx.x;
    int c = blockIdx.y;
    if (n < NPAD) {
        unsigned short b = 0;
        if (n < Nv) b = f2bf_rne(F[(size_t)n * Dd + c] * dvis[n]);   // F L3-resident (5 MB)
        Fst[(size_t)c * NPAD + n] = (short)b;
    }
}

// sum(F*F) -> ws0[0]
__global__ void sum_ff_kernel(const float* __restrict__ F, float* __restrict__ out0) {
    const float4* F4 = (const float4*)F;
    int base = blockIdx.x * 512 + threadIdx.x;      // 625*512 = 320000 = N*d/4 exactly
    float4 a = F4[base];
    float4 b = F4[base + 256];
    float sum = a.x*a.x + a.y*a.y + a.z*a.z + a.w*a.w
              + b.x*b.x + b.y*b.y + b.z*b.z + b.w*b.w;
    #pragma unroll
    for (int off = 32; off; off >>= 1) sum += __shfl_down(sum, off);
    if ((threadIdx.x & 63) == 0) atomicAdd(out0, sum);
}

// Split-K GEMM: Mp[split][e][c] = sum_{n in split} H[n,e]*Fs[n,c]
// 512 threads, 128e x 128c tile, dbuf LDS, 1 barrier/step, prefetched H, no atomics.
__global__ __launch_bounds__(512, 4)
void gemm_split_kernel(const float* __restrict__ H, const short* __restrict__ Fst,
                       float* __restrict__ Mp) {
    // Alds[buf][e][kk]: row stride 40 u32-halves = 80 B (16B-aligned b128 frag reads;
    // staging b32 writes land 2 lanes/bank = free)
    __shared__ unsigned int Alds[2][128 * 20];

    const int t   = threadIdx.x;
    const int w   = t >> 6;              // wave 0..7
    const int l   = t & 63;
    const int lm  = l & 15;
    const int q   = l >> 4;
    const int e0  = blockIdx.x * 128;
    const int we  = (w >> 1) * 32;       // wave e-offset {0,32,64,96}
    const int wc  = (w & 1) * 64;        // wave c-offset {0,64}
    const int spl = blockIdx.y;
    const int sb  = (spl * KSTEPS) / KSPLIT;
    const int se  = ((spl + 1) * KSTEPS) / KSPLIT;   // 26-27 steps/split

    const int rp  = t & 15;              // n-pair within K-chunk
    const int cpb = t >> 4;              // 0..31 col-pair base

    float2 hcur[2][2], hnxt[2][2];

    auto loadH = [&](int s, float2 (&h)[2][2]) {
        const int n = s * 32 + 2 * rp;   // Nv even -> pair shares validity
        #pragma unroll
        for (int j = 0; j < 2; ++j) {
            const int el = 2 * (cpb + 32 * j);
            const int e  = e0 + el;      // Ne even -> pair shares validity
            h[j][0] = make_float2(0.f, 0.f);
            h[j][1] = make_float2(0.f, 0.f);
            if (n < Nv && e < Ne) {
                h[j][0] = *(const float2*)(H + (size_t)n * Ne + e);
                h[j][1] = *(const float2*)(H + (size_t)(n + 1) * Ne + e);
            }
        }
    };
    auto writeLDS = [&](int buf, float2 (&h)[2][2]) {
        #pragma unroll
        for (int j = 0; j < 2; ++j) {
            const int el = 2 * (cpb + 32 * j);
            unsigned int w0 = (unsigned int)f2bf_rne(h[j][0].x) | ((unsigned int)f2bf_rne(h[j][1].x) << 16);
            unsigned int w1 = (unsigned int)f2bf_rne(h[j][0].y) | ((unsigned int)f2bf_rne(h[j][1].y) << 16);
            Alds[buf][el * 20 + rp]       = w0;   // row e,   kk = 2rp,2rp+1
            Alds[buf][(el + 1) * 20 + rp] = w1;   // row e+1
        }
    };

    f32x4 acc[2][4];
    #pragma unroll
    for (int a = 0; a < 2; ++a)
        #pragma unroll
        for (int b = 0; b < 4; ++b) acc[a][b] = (f32x4){0.f, 0.f, 0.f, 0.f};

    loadH(sb, hcur);
    writeLDS(0, hcur);
    __syncthreads();

    for (int s = sb; s < se; ++s) {
        const int buf = (s - sb) & 1;
        const int n0  = s * 32;

        if (s + 1 < se) loadH(s + 1, hnxt);   // prefetch next K-chunk (overlaps MFMA)

        bf16x8 Bf[4];                          // B frags direct from L2-hot Fst
        #pragma unroll
        for (int cb = 0; cb < 4; ++cb) {
            const int c = wc + cb * 16 + lm;
            Bf[cb] = *(const bf16x8*)(Fst + (size_t)c * NPAD + n0 + q * 8);
        }
        bf16x8 Af[2];
        #pragma unroll
        for (int eb = 0; eb < 2; ++eb) {
            const int el = we + eb * 16 + lm;
            Af[eb] = *(const bf16x8*)((const char*)Alds[buf] + el * 80 + q * 16);
        }

        #pragma unroll
        for (int cb = 0; cb < 4; ++cb)
            #pragma unroll
            for (int eb = 0; eb < 2; ++eb)
                acc[eb][cb] = __builtin_amdgcn_mfma_f32_16x16x32_bf16(
                    Af[eb], Bf[cb], acc[eb][cb], 0, 0, 0);

        if (s + 1 < se) writeLDS(buf ^ 1, hnxt);  // fill other buffer
        __syncthreads();                           // single barrier per step
    }

    // epilogue: C/D layout col = lane&15, row = quad*4 + reg; plain coalesced stores
    float* dst = Mp + (size_t)spl * EPAD * 128;
    #pragma unroll
    for (int eb = 0; eb < 2; ++eb) {
        #pragma unroll
        for (int cb = 0; cb < 4; ++cb) {
            const int c = wc + cb * 16 + lm;
            #pragma unroll
            for (int r = 0; r < 4; ++r) {
                const int el = we + eb * 16 + q * 4 + r;
                dst[(size_t)(e0 + el) * 128 + c] = acc[eb][cb][r];
            }
        }
    }
}

// S = sum_e de_inv[e]*||sum_split Mp[.,e,:]||^2 -> ws0[1]  (de_inv folded in)
__global__ void reduce_m_kernel(const float* __restrict__ Mp, const float* __restrict__ De,
                                float* __restrict__ outS) {
    int gid = blockIdx.x * 256 + threadIdx.x;   // 640*256 = 163840 = EPAD*32
    int e   = gid >> 5;
    int c4  = (gid & 31) * 4;
    float de_inv = (e < Ne) ? 1.0f / (De[(size_t)e * (Ne + 1)] + EPSF) : 0.0f;  // wave-broadcast
    float4 m = {0.f, 0.f, 0.f, 0.f};
    #pragma unroll
    for (int sp = 0; sp < KSPLIT; ++sp) {
        float4 p = *(const float4*)(Mp + (size_t)sp * EPAD * 128 + (size_t)e * 128 + c4);
        m.x += p.x; m.y += p.y; m.z += p.z; m.w += p.w;
    }
    float sum = de_inv * (m.x*m.x + m.y*m.y + m.z*m.z + m.w*m.w);
    #pragma unroll
    for (int off = 32; off; off >>= 1) sum += __shfl_down(sum, off);
    if ((threadIdx.x & 63) == 0) atomicAdd(outS, sum);
}

__global__ void final_kernel(const float* __restrict__ ws0, float* __restrict__ out) {
    out[0] = (ws0[0] - ws0[1]) * (1.0f / (float)Nv);
}

extern "C" void kernel_launch(void* const* d_in, const int* in_sizes, int n_in,
                              void* d_out, int out_size, void* d_ws, size_t ws_size,
                              hipStream_t stream) {
    (void)in_sizes; (void)n_in; (void)out_size; (void)ws_size;
    const float* F  = (const float*)d_in[0];
    const float* H  = (const float*)d_in[1];
    const float* Dv = (const float*)d_in[2];
    const float* De = (const float*)d_in[3];
    float* out = (float*)d_out;

    // ws layout: ws0(16 f) | dvis[NPAD] | Mp[KSPLIT*EPAD*128] | Fst bf16[128*NPAD]
    float* ws0  = (float*)d_ws;
    float* dvis = ws0 + 16;
    float* Mp   = dvis + NPAD;                       // offset 40128 B (16B-aligned)
    short* Fst  = (short*)(Mp + (size_t)KSPLIT * EPAD * 128);

    hipMemsetAsync(ws0, 0, 64, stream);              // only the two scalar accumulators

    prep_dv_kernel <<<(NPAD + 255) / 256, 256, 0, stream>>>(Dv, dvis);
    prep_fst_kernel<<<dim3((NPAD + 255) / 256, 128), 256, 0, stream>>>(F, dvis, Fst);
    sum_ff_kernel  <<<625, 256, 0, stream>>>(F, ws0);
    gemm_split_kernel<<<dim3(EPAD / 128, KSPLIT), 512, 0, stream>>>(H, Fst, Mp);
    reduce_m_kernel<<<640, 256, 0, stream>>>(Mp, De, ws0 + 1);
    final_kernel   <<<1, 1, 0, stream>>>(ws0, out);
}